// Round 1
// baseline (162.837 us; speedup 1.0000x reference)
//
#include <hip/hip_runtime.h>
#include <math.h>

#define BB   64
#define SS   576
#define DD   768
#define KTOP 63
#define KEEP 64
#define HH   128
#define NROW (BB*KEEP + BB)   // 4160 rows through the autoencoder

// ---------------- K1: cls attention scores (f64 accumulate for exact ranking) ---
__global__ __launch_bounds__(256) void k_scores(const float* __restrict__ cls,
                                                const float* __restrict__ fm,
                                                float* __restrict__ scores)
{
  int gw = (blockIdx.x * blockDim.x + threadIdx.x) >> 6;   // one wave per (b,s)
  int lane = threadIdx.x & 63;
  if (gw >= BB * SS) return;
  int b = gw / SS, s = gw - b * SS;
  const float4* frow = (const float4*)(fm + ((size_t)b * SS + s) * DD);
  const float4* crow = (const float4*)(cls + (size_t)b * DD);
  double acc = 0.0;
#pragma unroll
  for (int j = 0; j < 3; ++j) {
    float4 f = frow[lane + 64 * j];
    float4 c = crow[lane + 64 * j];
    acc += (double)f.x * c.x + (double)f.y * c.y + (double)f.z * c.z + (double)f.w * c.w;
  }
#pragma unroll
  for (int off = 32; off > 0; off >>= 1) acc += __shfl_down(acc, off, 64);
  if (lane == 0) scores[(size_t)b * SS + s] = (float)acc;
}

// ---------------- K2a: top-63 selection, sorted desc, ties -> lowest index -----
__global__ __launch_bounds__(64) void k_topk(const float* __restrict__ scores,
                                             int* __restrict__ idxout)
{
  int b = blockIdx.x, lane = threadIdx.x;
  unsigned long long key[9];
#pragma unroll
  for (int j = 0; j < 9; ++j) {
    int idx = lane + 64 * j;                       // covers 0..575
    unsigned int u = __float_as_uint(scores[(size_t)b * SS + idx]);
    u = (u & 0x80000000u) ? ~u : (u | 0x80000000u);   // order-preserving map
    key[j] = ((unsigned long long)u << 32) |
             (unsigned long long)(0xFFFFFFFFu - (unsigned)idx);  // ties: lower idx wins
  }
  for (int k = 0; k < KTOP; ++k) {
    unsigned long long best = key[0];
#pragma unroll
    for (int j = 1; j < 9; ++j) best = key[j] > best ? key[j] : best;
#pragma unroll
    for (int off = 32; off > 0; off >>= 1) {
      unsigned long long o = __shfl_xor(best, off, 64);
      best = o > best ? o : best;
    }
    int idx = (int)(0xFFFFFFFFu - (unsigned int)best);
    if (lane == 0) idxout[b * KEEP + k] = idx;
    if ((idx & 63) == lane) {                       // remove winner
      int wj = idx >> 6;
#pragma unroll
      for (int j = 0; j < 9; ++j) if (j == wj) key[j] = 0ull;
    }
  }
}

// ---------------- K2b: masked softmax weights + pooled extra token -------------
__global__ __launch_bounds__(256) void k_extra(const float* __restrict__ scores,
                                               const int* __restrict__ idxin,
                                               const float* __restrict__ fm,
                                               float* __restrict__ extra)
{
  __shared__ float w[SS];
  __shared__ unsigned char flag[SS];
  __shared__ float redm[4], redz[4];
  int b = blockIdx.x, tid = threadIdx.x;
  int d = blockIdx.y * 256 + tid;                   // grid.y = 3 -> d in 0..767
  for (int i = tid; i < SS; i += 256) { flag[i] = 0; w[i] = scores[(size_t)b * SS + i]; }
  __syncthreads();
  if (tid < KTOP) flag[idxin[b * KEEP + tid]] = 1;
  __syncthreads();
  // max over unselected (selected logits are score-10000 -> never the max)
  float m = -1e30f;
  for (int i = tid; i < SS; i += 256) if (!flag[i]) m = fmaxf(m, w[i]);
#pragma unroll
  for (int off = 32; off; off >>= 1) m = fmaxf(m, __shfl_xor(m, off, 64));
  if ((tid & 63) == 0) redm[tid >> 6] = m;
  __syncthreads();
  m = fmaxf(fmaxf(redm[0], redm[1]), fmaxf(redm[2], redm[3]));
  // e_s (selected -> exactly 0, matching f32 exp(-1e4) underflow in the reference)
  float zp = 0.f;
  for (int i = tid; i < SS; i += 256) {
    float e = flag[i] ? 0.f : expf(w[i] - m);
    w[i] = e; zp += e;
  }
#pragma unroll
  for (int off = 32; off; off >>= 1) zp += __shfl_xor(zp, off, 64);
  if ((tid & 63) == 0) redz[tid >> 6] = zp;
  __syncthreads();
  float Z = redz[0] + redz[1] + redz[2] + redz[3];
  // weighted sum over tokens for this dim slice (fm is L3-resident after K1)
  float acc = 0.f;
  const float* fcol = fm + (size_t)b * SS * DD + d;
#pragma unroll 8
  for (int s = 0; s < SS; ++s) acc += w[s] * fcol[(size_t)s * DD];
  extra[(size_t)b * DD + d] = acc / Z;
}

// ---------------- K3: gather rows + H = tanh(X @ W1 + b1) ----------------------
__global__ __launch_bounds__(256) void k_ae1(const float* __restrict__ fm,
                                             const float* __restrict__ cls,
                                             const float* __restrict__ extra,
                                             const int* __restrict__ idxin,
                                             const float* __restrict__ W1,
                                             const float* __restrict__ b1,
                                             float* __restrict__ H)
{
  __shared__ float Xt[16][DD];        // 48 KB
  __shared__ float Wt[32][HH];        // 16 KB
  __shared__ const float* rowptr[16];
  int tid = threadIdx.x;
  int rowbase = blockIdx.x * 16;      // 16-row tiles never cross a batch boundary
  if (tid < 16) {
    int row = rowbase + tid;
    const float* p;
    if (row < BB * KEEP) {
      int b = row >> 6, k = row & 63;
      p = (k < KTOP) ? fm + ((size_t)b * SS + idxin[b * KEEP + k]) * DD
                     : extra + (size_t)b * DD;
    } else {
      p = cls + (size_t)(row - BB * KEEP) * DD;
    }
    rowptr[tid] = p;
  }
  __syncthreads();
  for (int e = tid; e < 16 * (DD / 4); e += 256) {   // float4 gather into LDS
    int r = e / (DD / 4), k4 = e - r * (DD / 4);
    ((float4*)Xt[r])[k4] = ((const float4*)rowptr[r])[k4];
  }
  int rg = tid >> 5, cg = tid & 31;
  int r0 = rg * 2, c0 = cg * 4;
  float acc[2][4] = {};
  for (int kk = 0; kk < DD; kk += 32) {
    __syncthreads();
    for (int e = tid; e < 32 * (HH / 4); e += 256) {
      int k = e / (HH / 4), c4 = e - k * (HH / 4);
      ((float4*)Wt[k])[c4] = ((const float4*)(W1 + (size_t)(kk + k) * HH))[c4];
    }
    __syncthreads();
#pragma unroll
    for (int k = 0; k < 32; ++k) {
      float x0 = Xt[r0][kk + k], x1 = Xt[r0 + 1][kk + k];
      float4 wv = *(const float4*)&Wt[k][c0];
      acc[0][0] = fmaf(x0, wv.x, acc[0][0]); acc[0][1] = fmaf(x0, wv.y, acc[0][1]);
      acc[0][2] = fmaf(x0, wv.z, acc[0][2]); acc[0][3] = fmaf(x0, wv.w, acc[0][3]);
      acc[1][0] = fmaf(x1, wv.x, acc[1][0]); acc[1][1] = fmaf(x1, wv.y, acc[1][1]);
      acc[1][2] = fmaf(x1, wv.z, acc[1][2]); acc[1][3] = fmaf(x1, wv.w, acc[1][3]);
    }
  }
  float4 bv = *(const float4*)&b1[c0];
#pragma unroll
  for (int i = 0; i < 2; ++i) {
    int row = rowbase + r0 + i;
    float4 h;
    h.x = tanhf(acc[i][0] + bv.x);
    h.y = tanhf(acc[i][1] + bv.y);
    h.z = tanhf(acc[i][2] + bv.z);
    h.w = tanhf(acc[i][3] + bv.w);
    *(float4*)&H[(size_t)row * HH + c0] = h;
  }
}

// ---------------- K4: out = H @ W2 + b2  (rows 0..4159 map flat to d_out) ------
__global__ __launch_bounds__(256) void k_ae2(const float* __restrict__ H,
                                             const float* __restrict__ W2,
                                             const float* __restrict__ b2,
                                             float* __restrict__ out)
{
  __shared__ float Ht[16][HH];        // 8 KB
  __shared__ float Wt[HH][128];       // 64 KB
  int tid = threadIdx.x;
  int rowbase = blockIdx.x * 16;
  int cb = blockIdx.y * 128;
  for (int e = tid; e < 16 * (HH / 4); e += 256) {
    int r = e / (HH / 4), k4 = e - r * (HH / 4);
    ((float4*)Ht[r])[k4] = ((const float4*)(H + (size_t)(rowbase + r) * HH))[k4];
  }
  for (int e = tid; e < HH * 32; e += 256) {        // 128x128 W2 tile as float4
    int k = e >> 5, c4 = e & 31;
    ((float4*)Wt[k])[c4] = ((const float4*)(W2 + (size_t)k * DD + cb))[c4];
  }
  __syncthreads();
  int rg = tid >> 5, cg = tid & 31;
  int r0 = rg * 2, c0 = cg * 4;
  float acc[2][4] = {};
#pragma unroll 8
  for (int k = 0; k < HH; ++k) {
    float x0 = Ht[r0][k], x1 = Ht[r0 + 1][k];
    float4 wv = *(const float4*)&Wt[k][c0];
    acc[0][0] = fmaf(x0, wv.x, acc[0][0]); acc[0][1] = fmaf(x0, wv.y, acc[0][1]);
    acc[0][2] = fmaf(x0, wv.z, acc[0][2]); acc[0][3] = fmaf(x0, wv.w, acc[0][3]);
    acc[1][0] = fmaf(x1, wv.x, acc[1][0]); acc[1][1] = fmaf(x1, wv.y, acc[1][1]);
    acc[1][2] = fmaf(x1, wv.z, acc[1][2]); acc[1][3] = fmaf(x1, wv.w, acc[1][3]);
  }
  float4 bv = *(const float4*)&b2[cb + c0];
#pragma unroll
  for (int i = 0; i < 2; ++i) {
    int row = rowbase + r0 + i;
    float4 y;
    y.x = acc[i][0] + bv.x; y.y = acc[i][1] + bv.y;
    y.z = acc[i][2] + bv.z; y.w = acc[i][3] + bv.w;
    *(float4*)&out[(size_t)row * DD + cb + c0] = y;
  }
}

extern "C" void kernel_launch(void* const* d_in, const int* in_sizes, int n_in,
                              void* d_out, int out_size, void* d_ws, size_t ws_size,
                              hipStream_t stream)
{
  const float* cls = (const float*)d_in[0];
  const float* fm  = (const float*)d_in[1];
  const float* W1  = (const float*)d_in[2];
  const float* b1  = (const float*)d_in[3];
  const float* W2  = (const float*)d_in[4];
  const float* b2  = (const float*)d_in[5];
  float* out = (float*)d_out;

  char* ws = (char*)d_ws;
  float* scores = (float*)ws;                                  // 64*576*4   = 147456 B
  int*   idx    = (int*)(ws + 147456);                         // 64*64*4    =  16384 B
  float* extra  = (float*)(ws + 147456 + 16384);               // 64*768*4   = 196608 B
  float* H      = (float*)(ws + 147456 + 16384 + 196608);      // 4160*128*4 = 2129920 B

  hipLaunchKernelGGL(k_scores, dim3((BB * SS) / 4), dim3(256), 0, stream, cls, fm, scores);
  hipLaunchKernelGGL(k_topk,   dim3(BB),            dim3(64),  0, stream, scores, idx);
  hipLaunchKernelGGL(k_extra,  dim3(BB, 3),         dim3(256), 0, stream, scores, idx, fm, extra);
  hipLaunchKernelGGL(k_ae1,    dim3(NROW / 16),     dim3(256), 0, stream,
                     fm, cls, extra, idx, W1, b1, H);
  hipLaunchKernelGGL(k_ae2,    dim3(NROW / 16, DD / 128), dim3(256), 0, stream, H, W2, b2, out);
}